// Round 1
// baseline (554.680 us; speedup 1.0000x reference)
//
#include <hip/hip_runtime.h>

#define Bn 1024
#define Tn 256
#define Hn 128

typedef __attribute__((ext_vector_type(4))) float f32x4;
typedef __attribute__((ext_vector_type(8))) short short8;

__device__ __forceinline__ unsigned pack_bf16_2(float lo, float hi) {
    unsigned ul = __float_as_uint(lo), uh = __float_as_uint(hi);
    ul = (ul + 0x7fffu + ((ul >> 16) & 1u)) >> 16;
    uh = (uh + 0x7fffu + ((uh >> 16) & 1u)) >> 16;
    return (ul & 0xffffu) | (uh << 16);
}

__device__ __forceinline__ unsigned short f2bf(float f) {
    unsigned u = __float_as_uint(f);
    return (unsigned short)((u + 0x7fffu + ((u >> 16) & 1u)) >> 16);
}

__launch_bounds__(256, 1)
__global__ void bandit_rnn(const float* __restrict__ x,
                           const float* __restrict__ Wxr, const float* __restrict__ Wxz, const float* __restrict__ Wxn,
                           const float* __restrict__ Whr, const float* __restrict__ Whz, const float* __restrict__ Whn,
                           const float* __restrict__ bxr, const float* __restrict__ bxz, const float* __restrict__ bxn,
                           const float* __restrict__ brh, const float* __restrict__ bzh, const float* __restrict__ bnh,
                           const float* __restrict__ Wout, const float* __restrict__ bout,
                           float* __restrict__ out) {
    // LDS
    __shared__ f32x4 comb0[512], comb1[512], comb2[512];   // [k*128+i]: {Wx row, combined bias}
    __shared__ float combB[512];                           // bnh[k*128+i]
    __shared__ __align__(16) float pre[12 * 132];          // [gate*4+chain][132] preacts
    __shared__ float h32[4 * 128];                         // f32 recurrent state
    __shared__ __align__(16) unsigned short h16[4 * 136];  // bf16 state for MFMA B-frags
    __shared__ float WoutL[256];
    __shared__ float xs[4][3];
    __shared__ unsigned modesU;                            // 4 mode bytes

    const int tid = threadIdx.x;
    const int w = tid >> 6;       // wave id == local chain id (4 waves)
    const int lane = tid & 63;
    const int cb = blockIdx.x * 4;

    // ---------------- prologue ----------------
    for (int p = tid; p < 512; p += 256) h32[p] = 0.f;
    for (int p = tid; p < 544; p += 256) h16[p] = 0;

    for (int p = tid; p < 512; p += 256) {
        int k = p >> 7, i = p & 127;
        const float* wr = Wxr + (k * 128 + i) * 3;
        const float* wz = Wxz + (k * 128 + i) * 3;
        const float* wn = Wxn + (k * 128 + i) * 3;
        comb0[p] = (f32x4){wr[0], wr[1], wr[2], bxr[p] + brh[p]};
        comb1[p] = (f32x4){wz[0], wz[1], wz[2], bxz[p] + bzh[p]};
        comb2[p] = (f32x4){wn[0], wn[1], wn[2], bxn[p]};
        combB[p] = bnh[p];
    }
    if (tid < 256) WoutL[tid] = Wout[tid];
    const float b0 = bout[0], b1 = bout[1];

    if (lane == 0) {
        const float* xp = x + (size_t)(cb + w) * Tn * 3;
        float x0 = xp[0], x1 = xp[1], x2 = xp[2];
        xs[w][0] = x0; xs[w][1] = x1; xs[w][2] = x2;
        int a = (x1 > x0) ? 1 : 0;
        int rr = (x2 > 0.5f) ? 1 : 0;
        ((unsigned char*)&modesU)[w] = (unsigned char)(a + 2 * rr);
    }

    // register-stationary weight fragments: wave w owns rows [32w,32w+32) of every
    // (gate,expert) matrix -> absent-expert skip is balanced across waves.
    const int r16 = lane & 15, q = lane >> 4;
    short8 Afr[3][4][2][4];
    {
        const float* Wh[3] = {Whr, Whz, Whn};
#pragma unroll
        for (int g = 0; g < 3; ++g)
#pragma unroll
        for (int e = 0; e < 4; ++e)
#pragma unroll
        for (int mt = 0; mt < 2; ++mt)
#pragma unroll
        for (int kt = 0; kt < 4; ++kt) {
            const float* p = Wh[g] + (((e * 128) + (32 * w + 16 * mt + r16)) * 128 + 32 * kt + 8 * q);
            float4 a0 = *(const float4*)p;
            float4 a1 = *(const float4*)(p + 4);
            union { short8 s; unsigned u[4]; } fr;
            fr.u[0] = pack_bf16_2(a0.x, a0.y);
            fr.u[1] = pack_bf16_2(a0.z, a0.w);
            fr.u[2] = pack_bf16_2(a1.x, a1.y);
            fr.u[3] = pack_bf16_2(a1.z, a1.w);
            Afr[g][e][mt][kt] = fr.s;
        }
    }
    __syncthreads();

    const int cc = r16 & 3;  // B-column chain (duplicated for r16>=4)

    // ---------------- time loop ----------------
    for (int t = 0; t < Tn; ++t) {
        unsigned m = modesU;
        unsigned pres = (1u << (m & 3)) | (1u << ((m >> 8) & 3)) |
                        (1u << ((m >> 16) & 3)) | (1u << ((m >> 24) & 3));
        int mode_c = (m >> (8 * cc)) & 3;
        bool cval = (r16 < 4);

        // B fragments from bf16 h state
        short8 Bf[4];
#pragma unroll
        for (int kt = 0; kt < 4; ++kt)
            Bf[kt] = *(const short8*)&h16[cc * 136 + 32 * kt + 8 * q];

#pragma unroll
        for (int e = 0; e < 4; ++e) {
            if (!(pres & (1u << e))) continue;   // wave-uniform skip
            f32x4 acc[3][2];
#pragma unroll
            for (int g = 0; g < 3; ++g)
#pragma unroll
            for (int mt = 0; mt < 2; ++mt) {
                acc[g][mt] = (f32x4){0.f, 0.f, 0.f, 0.f};
#pragma unroll
                for (int kt = 0; kt < 4; ++kt)
                    acc[g][mt] = __builtin_amdgcn_mfma_f32_16x16x32_bf16(
                        Afr[g][e][mt][kt], Bf[kt], acc[g][mt], 0, 0, 0);
            }
            if (cval && mode_c == e) {
#pragma unroll
                for (int g = 0; g < 3; ++g)
#pragma unroll
                for (int mt = 0; mt < 2; ++mt) {
                    int i0 = 32 * w + 16 * mt + 4 * q;
                    *(f32x4*)&pre[(g * 4 + cc) * 132 + i0] = acc[g][mt];
                }
            }
        }
        __syncthreads();

        // nonlinearity: wave w handles chain w densely (2 elems/thread)
        {
            int kk = (m >> (8 * w)) & 3;
            float x0 = xs[w][0], x1 = xs[w][1], x2 = xs[w][2];
            float s0 = 0.f, s1 = 0.f;
#pragma unroll
            for (int half = 0; half < 2; ++half) {
                int i = lane + 64 * half;
                float pr = pre[(0 * 4 + w) * 132 + i];
                float pz = pre[(1 * 4 + w) * 132 + i];
                float ph = pre[(2 * 4 + w) * 132 + i];
                f32x4 c0 = comb0[kk * 128 + i];
                f32x4 c1 = comb1[kk * 128 + i];
                f32x4 c2 = comb2[kk * 128 + i];
                float bn = combB[kk * 128 + i];
                float rp = pr + c0[3] + c0[0] * x0 + c0[1] * x1 + c0[2] * x2;
                float zp = pz + c1[3] + c1[0] * x0 + c1[1] * x1 + c1[2] * x2;
                float xn = c2[3] + c2[0] * x0 + c2[1] * x1 + c2[2] * x2;
                float r = 1.f / (1.f + __expf(-rp));
                float z = 1.f / (1.f + __expf(-zp));
                float np = xn + r * (ph + bn);
                float ex = __expf(2.f * np);
                float n = 1.f - 2.f / (ex + 1.f);
                float hp = h32[w * 128 + i];
                float h = n + z * (hp - n);
                h32[w * 128 + i] = h;
                h16[w * 136 + i] = f2bf(h);
                s0 += h * WoutL[i];
                s1 += h * WoutL[128 + i];
            }
#pragma unroll
            for (int off = 32; off; off >>= 1) {
                s0 += __shfl_xor(s0, off);
                s1 += __shfl_xor(s1, off);
            }
            if (lane == 0) {
                float2 lg = make_float2(s0 + b0, s1 + b1);
                *(float2*)(out + ((size_t)(cb + w) * Tn + t) * 2) = lg;
                if (t + 1 < Tn) {   // prefetch next x + mode (selector is h-independent)
                    const float* xp = x + ((size_t)(cb + w) * Tn + (t + 1)) * 3;
                    float nx0 = xp[0], nx1 = xp[1], nx2 = xp[2];
                    xs[w][0] = nx0; xs[w][1] = nx1; xs[w][2] = nx2;
                    int a = (nx1 > nx0) ? 1 : 0;
                    int rr2 = (nx2 > 0.5f) ? 1 : 0;
                    ((unsigned char*)&modesU)[w] = (unsigned char)(a + 2 * rr2);
                }
            }
        }
        __syncthreads();
    }

    // final hidden state hT -> out[B*T*A ..]
    for (int p = tid; p < 512; p += 256) {
        int c = p >> 7, i = p & 127;
        out[524288 + (size_t)(cb + c) * 128 + i] = h32[c * 128 + i];
    }
}

extern "C" void kernel_launch(void* const* d_in, const int* in_sizes, int n_in,
                              void* d_out, int out_size, void* d_ws, size_t ws_size,
                              hipStream_t stream) {
    const float* xin = (const float*)d_in[0];
    const float* Wxr = (const float*)d_in[1];
    const float* Wxz = (const float*)d_in[2];
    const float* Wxn = (const float*)d_in[3];
    const float* Whr = (const float*)d_in[4];
    const float* Whz = (const float*)d_in[5];
    const float* Whn = (const float*)d_in[6];
    const float* bxr = (const float*)d_in[7];
    const float* bxz = (const float*)d_in[8];
    const float* bxn = (const float*)d_in[9];
    const float* brh = (const float*)d_in[10];
    const float* bzh = (const float*)d_in[11];
    const float* bnh = (const float*)d_in[12];
    const float* Wout = (const float*)d_in[13];
    const float* bout = (const float*)d_in[14];
    float* outp = (float*)d_out;

    hipLaunchKernelGGL(bandit_rnn, dim3(256), dim3(256), 0, stream,
                       xin, Wxr, Wxz, Wxn, Whr, Whz, Whn,
                       bxr, bxz, bxn, brh, bzh, bnh, Wout, bout, outp);
}

// Round 2
// 417.876 us; speedup vs baseline: 1.3274x; 1.3274x over previous
//
#include <hip/hip_runtime.h>

#define Bn 1024
#define Tn 256
#define Hn 128

typedef __attribute__((ext_vector_type(4))) float f32x4;
typedef __attribute__((ext_vector_type(8))) short short8;

__device__ __forceinline__ unsigned pack_bf16_2(float lo, float hi) {
    unsigned ul = __float_as_uint(lo), uh = __float_as_uint(hi);
    ul = (ul + 0x7fffu + ((ul >> 16) & 1u)) >> 16;
    uh = (uh + 0x7fffu + ((uh >> 16) & 1u)) >> 16;
    return (ul & 0xffffu) | (uh << 16);
}

__device__ __forceinline__ unsigned short f2bf(float f) {
    unsigned u = __float_as_uint(f);
    return (unsigned short)((u + 0x7fffu + ((u >> 16) & 1u)) >> 16);
}

__launch_bounds__(512, 2)
__global__ void bandit_rnn(const float* __restrict__ x,
                           const float* __restrict__ Wxr, const float* __restrict__ Wxz, const float* __restrict__ Wxn,
                           const float* __restrict__ Whr, const float* __restrict__ Whz, const float* __restrict__ Whn,
                           const float* __restrict__ bxr, const float* __restrict__ bxz, const float* __restrict__ bxn,
                           const float* __restrict__ brh, const float* __restrict__ bzh, const float* __restrict__ bnh,
                           const float* __restrict__ Wout, const float* __restrict__ bout,
                           float* __restrict__ out) {
    // LDS
    __shared__ f32x4 comb0[512], comb1[512], comb2[512];   // [k*128+i]: {Wx row, combined bias}
    __shared__ float combB[512];                           // bnh[k*128+i]
    __shared__ __align__(16) float pre[12 * 132];          // [gate*4+chain][132] preacts
    __shared__ float h32[4 * 128];                         // f32 recurrent state
    __shared__ __align__(16) unsigned short h16[4 * 136];  // bf16 state for MFMA B-frags
    __shared__ float WoutL[256];
    __shared__ float xs[2][4][3];                          // double-buffered x_t
    __shared__ unsigned modesArr[Tn];                      // packed mode bytes per step
    __shared__ float sp[8][2];                             // per-wave logit partials

    const int tid = threadIdx.x;
    const int w = tid >> 6;       // 8 waves
    const int lane = tid & 63;
    const int cb = blockIdx.x * 4;

    // ---------------- prologue ----------------
    if (tid < 512) { h32[tid] = 0.f; }
    for (int p = tid; p < 544; p += 512) h16[p] = 0;

    if (tid < 512) {
        int p = tid;
        int k = p >> 7, i = p & 127;
        const float* wr = Wxr + (k * 128 + i) * 3;
        const float* wz = Wxz + (k * 128 + i) * 3;
        const float* wn = Wxn + (k * 128 + i) * 3;
        comb0[p] = (f32x4){wr[0], wr[1], wr[2], bxr[p] + brh[p]};
        comb1[p] = (f32x4){wz[0], wz[1], wz[2], bxz[p] + bzh[p]};
        comb2[p] = (f32x4){wn[0], wn[1], wn[2], bxn[p]};
        combB[p] = bnh[p];
    }
    if (tid < 256) WoutL[tid] = Wout[tid];
    const float b0 = bout[0], b1 = bout[1];

    // precompute all mode words (selector depends only on x)
    if (tid < Tn) {
        const float* xp = x + (size_t)cb * (Tn * 3) + tid * 3;
        unsigned mword = 0;
#pragma unroll
        for (int c = 0; c < 4; ++c) {
            float x0 = xp[c * Tn * 3 + 0];
            float x1 = xp[c * Tn * 3 + 1];
            float x2 = xp[c * Tn * 3 + 2];
            unsigned mode = ((x1 > x0) ? 1u : 0u) + ((x2 > 0.5f) ? 2u : 0u);
            mword |= mode << (8 * c);
        }
        modesArr[tid] = mword;
    }
    if (tid < 12) {
        int c = tid / 3, j = tid % 3;
        xs[0][c][j] = x[(size_t)(cb + c) * (Tn * 3) + j];
    }

    // register-stationary weights: wave w owns rows [16w,16w+16) of every
    // (gate,expert) matrix. 48 short8 = 192 arch VGPRs.
    const int r16 = lane & 15, q = lane >> 4;
    short8 Afr[3][4][4];
    {
        const float* Wh[3] = {Whr, Whz, Whn};
#pragma unroll
        for (int g = 0; g < 3; ++g)
#pragma unroll
        for (int e = 0; e < 4; ++e)
#pragma unroll
        for (int kt = 0; kt < 4; ++kt) {
            const float* p = Wh[g] + (((e * 128) + (16 * w + r16)) * 128 + 32 * kt + 8 * q);
            float4 a0 = *(const float4*)p;
            float4 a1 = *(const float4*)(p + 4);
            union { short8 s; unsigned u[4]; } fr;
            fr.u[0] = pack_bf16_2(a0.x, a0.y);
            fr.u[1] = pack_bf16_2(a0.z, a0.w);
            fr.u[2] = pack_bf16_2(a1.x, a1.y);
            fr.u[3] = pack_bf16_2(a1.z, a1.w);
            Afr[g][e][kt] = fr.s;
        }
    }
    __syncthreads();

    const int cc = r16 & 3;        // B-column chain (duplicated for r16>=4)
    const int cnl = w >> 1;        // nonlinearity: chain per wave-pair
    const int inl = ((w & 1) << 6) | lane;  // element index within chain

    // ---------------- time loop ----------------
    for (int t = 0; t < Tn; ++t) {
        // deferred logit store for step t-1 (sp written in phase 2 of t-1)
        if (t > 0 && tid < 4) {
            int c = tid;
            float s0 = sp[2 * c][0] + sp[2 * c + 1][0] + b0;
            float s1 = sp[2 * c][1] + sp[2 * c + 1][1] + b1;
            *(float2*)(out + ((size_t)(cb + c) * Tn + (t - 1)) * 2) = make_float2(s0, s1);
        }
        // prefetch x_{t+1}
        if (t + 1 < Tn && tid < 12) {
            int c = tid / 3, j = tid % 3;
            xs[(t + 1) & 1][c][j] = x[(size_t)(cb + c) * (Tn * 3) + (t + 1) * 3 + j];
        }

        unsigned m = modesArr[t];
        unsigned pres = (1u << (m & 3)) | (1u << ((m >> 8) & 3)) |
                        (1u << ((m >> 16) & 3)) | (1u << ((m >> 24) & 3));
        int mode_c = (m >> (8 * cc)) & 3;
        bool cval = (r16 < 4);

        // B fragments from bf16 h state
        short8 Bf[4];
#pragma unroll
        for (int kt = 0; kt < 4; ++kt)
            Bf[kt] = *(const short8*)&h16[cc * 136 + 32 * kt + 8 * q];

#pragma unroll
        for (int e = 0; e < 4; ++e) {
            if (!(pres & (1u << e))) continue;   // block-uniform skip
            f32x4 acc[3];
#pragma unroll
            for (int g = 0; g < 3; ++g) {
                acc[g] = (f32x4){0.f, 0.f, 0.f, 0.f};
#pragma unroll
                for (int kt = 0; kt < 4; ++kt)
                    acc[g] = __builtin_amdgcn_mfma_f32_16x16x32_bf16(
                        Afr[g][e][kt], Bf[kt], acc[g], 0, 0, 0);
            }
            if (cval && mode_c == e) {
                int i0 = 16 * w + 4 * q;
#pragma unroll
                for (int g = 0; g < 3; ++g)
                    *(f32x4*)&pre[(g * 4 + cc) * 132 + i0] = acc[g];
            }
        }
        __syncthreads();

        // nonlinearity: wave-pair (2 waves) per chain, 1 elem/thread
        {
            int kk = (m >> (8 * cnl)) & 3;
            float x0 = xs[t & 1][cnl][0], x1 = xs[t & 1][cnl][1], x2 = xs[t & 1][cnl][2];
            int i = inl;
            float pr = pre[(0 * 4 + cnl) * 132 + i];
            float pz = pre[(1 * 4 + cnl) * 132 + i];
            float ph = pre[(2 * 4 + cnl) * 132 + i];
            f32x4 c0 = comb0[kk * 128 + i];
            f32x4 c1 = comb1[kk * 128 + i];
            f32x4 c2 = comb2[kk * 128 + i];
            float bn = combB[kk * 128 + i];
            float rp = pr + c0[3] + c0[0] * x0 + c0[1] * x1 + c0[2] * x2;
            float zp = pz + c1[3] + c1[0] * x0 + c1[1] * x1 + c1[2] * x2;
            float xn = c2[3] + c2[0] * x0 + c2[1] * x1 + c2[2] * x2;
            float r = 1.f / (1.f + __expf(-rp));
            float z = 1.f / (1.f + __expf(-zp));
            float np = xn + r * (ph + bn);
            float ex = __expf(2.f * np);
            float n = 1.f - 2.f / (ex + 1.f);
            float hp = h32[cnl * 128 + i];
            float h = n + z * (hp - n);
            h32[cnl * 128 + i] = h;
            h16[cnl * 136 + i] = f2bf(h);
            float s0 = h * WoutL[i];
            float s1 = h * WoutL[128 + i];
#pragma unroll
            for (int off = 32; off; off >>= 1) {
                s0 += __shfl_xor(s0, off);
                s1 += __shfl_xor(s1, off);
            }
            if (lane == 0) { sp[w][0] = s0; sp[w][1] = s1; }
        }
        __syncthreads();
    }

    // flush last logits (t = Tn-1)
    if (tid < 4) {
        int c = tid;
        float s0 = sp[2 * c][0] + sp[2 * c + 1][0] + b0;
        float s1 = sp[2 * c][1] + sp[2 * c + 1][1] + b1;
        *(float2*)(out + ((size_t)(cb + c) * Tn + (Tn - 1)) * 2) = make_float2(s0, s1);
    }
    // final hidden state hT
    if (tid < 512) {
        int c = tid >> 7, i = tid & 127;
        out[(size_t)Bn * Tn * 2 + (size_t)(cb + c) * 128 + i] = h32[c * 128 + i];
    }
}

extern "C" void kernel_launch(void* const* d_in, const int* in_sizes, int n_in,
                              void* d_out, int out_size, void* d_ws, size_t ws_size,
                              hipStream_t stream) {
    const float* xin = (const float*)d_in[0];
    const float* Wxr = (const float*)d_in[1];
    const float* Wxz = (const float*)d_in[2];
    const float* Wxn = (const float*)d_in[3];
    const float* Whr = (const float*)d_in[4];
    const float* Whz = (const float*)d_in[5];
    const float* Whn = (const float*)d_in[6];
    const float* bxr = (const float*)d_in[7];
    const float* bxz = (const float*)d_in[8];
    const float* bxn = (const float*)d_in[9];
    const float* brh = (const float*)d_in[10];
    const float* bzh = (const float*)d_in[11];
    const float* bnh = (const float*)d_in[12];
    const float* Wout = (const float*)d_in[13];
    const float* bout = (const float*)d_in[14];
    float* outp = (float*)d_out;

    hipLaunchKernelGGL(bandit_rnn, dim3(256), dim3(512), 0, stream,
                       xin, Wxr, Wxz, Wxn, Whr, Whz, Whn,
                       bxr, bxz, bxn, brh, bzh, bnh, Wout, bout, outp);
}

// Round 4
// 350.844 us; speedup vs baseline: 1.5810x; 1.1911x over previous
//
#include <hip/hip_runtime.h>

#define Bn 1024
#define Tn 256

typedef __attribute__((ext_vector_type(4))) float f32x4;
typedef __attribute__((ext_vector_type(2))) float f32x2;
typedef __attribute__((ext_vector_type(8))) short short8;

static __device__ __forceinline__ unsigned pack_bf16_2(float lo, float hi) {
    unsigned ul = __float_as_uint(lo), uh = __float_as_uint(hi);
    ul = (ul + 0x7fffu + ((ul >> 16) & 1u)) >> 16;
    uh = (uh + 0x7fffu + ((uh >> 16) & 1u)) >> 16;
    return (ul & 0xffffu) | (uh << 16);
}

static __device__ __forceinline__ unsigned short f2bf(float f) {
    unsigned u = __float_as_uint(f);
    return (unsigned short)((u + 0x7fffu + ((u >> 16) & 1u)) >> 16);
}

__launch_bounds__(512, 2)
__global__ void bandit_rnn(const float* __restrict__ x,
                           const float* __restrict__ Wxr, const float* __restrict__ Wxz, const float* __restrict__ Wxn,
                           const float* __restrict__ Whr, const float* __restrict__ Whz, const float* __restrict__ Whn,
                           const float* __restrict__ bxr, const float* __restrict__ bxz, const float* __restrict__ bxn,
                           const float* __restrict__ brh, const float* __restrict__ bzh, const float* __restrict__ bnh,
                           const float* __restrict__ Wout, const float* __restrict__ bout,
                           float* __restrict__ out) {
    __shared__ f32x4 comb0[512], comb1[512], comb2[512];    // [k*128+row]: {Wx row, bias}
    __shared__ float combB[512];                            // bnh
    __shared__ __align__(16) unsigned short h16[2][4][136]; // double-buffered bf16 h
    __shared__ float WoutL[256];
    __shared__ float xs[2][4][3];                           // double-buffered x_t
    __shared__ unsigned modesArr[Tn];
    __shared__ __align__(16) float spbuf[2][8][4][2];       // double-buffered logit partials

    const int tid = threadIdx.x;
    const int w = tid >> 6;       // 8 waves
    const int lane = tid & 63;
    const int r16 = lane & 15, q = lane >> 4;
    const int cb = blockIdx.x * 4;

    // ---------------- prologue ----------------
    for (int p = tid; p < 2 * 4 * 136; p += 512) ((unsigned short*)h16)[p] = 0;
    {
        int p = tid;              // 512 threads == 512 table rows
        int k = p >> 7, i = p & 127;
        const float* wr = Wxr + (k * 128 + i) * 3;
        const float* wz = Wxz + (k * 128 + i) * 3;
        const float* wn = Wxn + (k * 128 + i) * 3;
        comb0[p] = (f32x4){wr[0], wr[1], wr[2], bxr[p] + brh[p]};
        comb1[p] = (f32x4){wz[0], wz[1], wz[2], bxz[p] + bzh[p]};
        comb2[p] = (f32x4){wn[0], wn[1], wn[2], bxn[p]};
        combB[p] = bnh[p];
    }
    if (tid < 256) WoutL[tid] = Wout[tid];
    const float b0 = bout[0], b1 = bout[1];

    if (tid < Tn) {               // all mode words (selector depends only on x)
        const float* xp = x + (size_t)cb * (Tn * 3) + tid * 3;
        unsigned mword = 0;
#pragma unroll
        for (int c = 0; c < 4; ++c) {
            float x0 = xp[c * Tn * 3 + 0];
            float x1 = xp[c * Tn * 3 + 1];
            float x2 = xp[c * Tn * 3 + 2];
            unsigned mode = ((x1 > x0) ? 1u : 0u) + ((x2 > 0.5f) ? 2u : 0u);
            mword |= mode << (8 * c);
        }
        modesArr[tid] = mword;
    }
    if (tid < 12) {
        int c = tid / 3, j = tid % 3;
        xs[0][c][j] = x[(size_t)(cb + c) * (Tn * 3) + j];
    }

    // weights: wave w owns rows [16w,16w+16); 48 short8 = 192 VGPRs
    short8 Afr[3][4][4];
    {
        const float* Wh[3] = {Whr, Whz, Whn};
#pragma unroll
        for (int g = 0; g < 3; ++g)
#pragma unroll
        for (int e = 0; e < 4; ++e)
#pragma unroll
        for (int kt = 0; kt < 4; ++kt) {
            const float* p = Wh[g] + (((e * 128) + (16 * w + r16)) * 128 + 32 * kt + 8 * q);
            float4 a0 = *(const float4*)p;
            float4 a1 = *(const float4*)(p + 4);
            union { short8 s; unsigned u[4]; } fr;
            fr.u[0] = pack_bf16_2(a0.x, a0.y);
            fr.u[1] = pack_bf16_2(a0.z, a0.w);
            fr.u[2] = pack_bf16_2(a1.x, a1.y);
            fr.u[3] = pack_bf16_2(a1.z, a1.w);
            Afr[g][e][kt] = fr.s;
        }
    }

    // per-lane nonlin assignment: chain c = r16&3, local row j* = r16>>2,
    // global row = 16w + 4q + j*  (valid because B-cols 4..15 duplicate chains 0..3)
    const int cc = r16 & 3;
    const bool jb0 = ((r16 >> 2) & 1) != 0;
    const bool jb1 = ((r16 >> 2) & 2) != 0;
    const int row = 16 * w + 4 * q + (r16 >> 2);
    float hpv = 0.f;              // f32 recurrent state (1 per lane)
    __syncthreads();

    // ---------------- time loop: ONE barrier per step ----------------
#pragma unroll 1
    for (int t = 0; t < Tn; ++t) {
        const int tb = t & 1;
        // flush logits of step t-1 (spbuf double-buffered)
        if (t > 0 && tid < 8) {
            int c = tid >> 1, a = tid & 1;
            float s = a ? b1 : b0;
#pragma unroll
            for (int wv = 0; wv < 8; ++wv) s += spbuf[tb ^ 1][wv][c][a];
            out[((size_t)(cb + c) * Tn + (t - 1)) * 2 + a] = s;
        }
        // issue x_{t+1} load early; LDS write deferred past the MFMAs
        float xpre = 0.f; int xc = 0, xj = 0;
        if (t + 1 < Tn && tid < 12) {
            xc = tid / 3; xj = tid % 3;
            xpre = x[(size_t)(cb + xc) * (Tn * 3) + (t + 1) * 3 + xj];
        }

        const unsigned m = modesArr[t];
        const unsigned pres = (1u << (m & 3)) | (1u << ((m >> 8) & 3)) |
                              (1u << ((m >> 16) & 3)) | (1u << ((m >> 24) & 3));
        const int mode_c = (m >> (8 * cc)) & 3;

        short8 Bf[4];
#pragma unroll
        for (int kt = 0; kt < 4; ++kt)
            Bf[kt] = *(const short8*)&h16[tb][cc][32 * kt + 8 * q];

        float selR = 0.f, selZ = 0.f, selN = 0.f;
#pragma unroll
        for (int e = 0; e < 4; ++e) {
            if (!(pres & (1u << e))) continue;   // block-uniform skip
            f32x4 aR = (f32x4){0.f, 0.f, 0.f, 0.f};
            f32x4 aZ = (f32x4){0.f, 0.f, 0.f, 0.f};
            f32x4 aN = (f32x4){0.f, 0.f, 0.f, 0.f};
#pragma unroll
            for (int kt = 0; kt < 4; ++kt) {
                aR = __builtin_amdgcn_mfma_f32_16x16x32_bf16(Afr[0][e][kt], Bf[kt], aR, 0, 0, 0);
                aZ = __builtin_amdgcn_mfma_f32_16x16x32_bf16(Afr[1][e][kt], Bf[kt], aZ, 0, 0, 0);
                aN = __builtin_amdgcn_mfma_f32_16x16x32_bf16(Afr[2][e][kt], Bf[kt], aN, 0, 0, 0);
            }
            // per-lane scalar select of element j* = r16>>2, then mode-match select
            float vR = jb1 ? (jb0 ? aR[3] : aR[2]) : (jb0 ? aR[1] : aR[0]);
            float vZ = jb1 ? (jb0 ? aZ[3] : aZ[2]) : (jb0 ? aZ[1] : aZ[0]);
            float vN = jb1 ? (jb0 ? aN[3] : aN[2]) : (jb0 ? aN[1] : aN[0]);
            bool mym = (mode_c == e);
            selR = mym ? vR : selR;
            selZ = mym ? vZ : selZ;
            selN = mym ? vN : selN;
        }
        if (t + 1 < Tn && tid < 12) xs[tb ^ 1][xc][xj] = xpre;

        // all-64-lane fused nonlinearity: lane owns (chain cc, row)
        {
            const int kk = mode_c;                 // expert of this lane's chain
            float x0 = xs[tb][cc][0], x1 = xs[tb][cc][1], x2 = xs[tb][cc][2];
            f32x4 c0 = comb0[kk * 128 + row];
            f32x4 c1 = comb1[kk * 128 + row];
            f32x4 c2 = comb2[kk * 128 + row];
            float bn = combB[kk * 128 + row];
            float rp = selR + c0[3] + c0[0] * x0 + c0[1] * x1 + c0[2] * x2;
            float zp = selZ + c1[3] + c1[0] * x0 + c1[1] * x1 + c1[2] * x2;
            float xn =        c2[3] + c2[0] * x0 + c2[1] * x1 + c2[2] * x2;
            float r = 1.f / (1.f + __expf(-rp));
            float z = 1.f / (1.f + __expf(-zp));
            float npv = xn + r * (selN + bn);
            float ex = __expf(2.f * npv);
            float n = 1.f - 2.f / (ex + 1.f);
            float h = n + z * (hpv - n);
            hpv = h;
            h16[tb ^ 1][cc][row] = f2bf(h);
            float s0 = h * WoutL[row];
            float s1 = h * WoutL[128 + row];
            // reduce over the 16-lane group sharing chain cc (masks 4,8 span j*, 16,32 span q)
            s0 += __shfl_xor(s0, 4);  s1 += __shfl_xor(s1, 4);
            s0 += __shfl_xor(s0, 8);  s1 += __shfl_xor(s1, 8);
            s0 += __shfl_xor(s0, 16); s1 += __shfl_xor(s1, 16);
            s0 += __shfl_xor(s0, 32); s1 += __shfl_xor(s1, 32);
            if (lane < 4) *(f32x2*)&spbuf[tb][w][lane][0] = (f32x2){s0, s1};
        }
        __syncthreads();
    }

    // flush last logits (t = Tn-1; buffer (Tn-1)&1 == 1)
    if (tid < 8) {
        int c = tid >> 1, a = tid & 1;
        float s = a ? b1 : b0;
#pragma unroll
        for (int wv = 0; wv < 8; ++wv) s += spbuf[1][wv][c][a];
        out[((size_t)(cb + c) * Tn + (Tn - 1)) * 2 + a] = s;
    }
    // final hidden state hT from registers (one element per lane)
    out[(size_t)Bn * Tn * 2 + (size_t)(cb + cc) * 128 + row] = hpv;
}

extern "C" void kernel_launch(void* const* d_in, const int* in_sizes, int n_in,
                              void* d_out, int out_size, void* d_ws, size_t ws_size,
                              hipStream_t stream) {
    const float* xin = (const float*)d_in[0];
    const float* Wxr = (const float*)d_in[1];
    const float* Wxz = (const float*)d_in[2];
    const float* Wxn = (const float*)d_in[3];
    const float* Whr = (const float*)d_in[4];
    const float* Whz = (const float*)d_in[5];
    const float* Whn = (const float*)d_in[6];
    const float* bxr = (const float*)d_in[7];
    const float* bxz = (const float*)d_in[8];
    const float* bxn = (const float*)d_in[9];
    const float* brh = (const float*)d_in[10];
    const float* bzh = (const float*)d_in[11];
    const float* bnh = (const float*)d_in[12];
    const float* Wout = (const float*)d_in[13];
    const float* bout = (const float*)d_in[14];
    float* outp = (float*)d_out;

    hipLaunchKernelGGL(bandit_rnn, dim3(256), dim3(512), 0, stream,
                       xin, Wxr, Wxz, Wxn, Whr, Whz, Whn,
                       bxr, bxz, bxn, brh, bzh, bnh, Wout, bout, outp);
}